// Round 4
// baseline (122.019 us; speedup 1.0000x reference)
//
#include <hip/hip_runtime.h>

// Problem constants (from reference): B=4, N=64, S=512, D=128, H=8
#define Bsz 4
#define Ngrp 64
#define Sset 512
#define Din 128
#define Hh 8
#define EST (Sset + 1)  // padded LDS stride for e rows

// DPP-based add over lanes: masks {1,2,7,15} generate the full 16-lane group,
// so 4 steps give every lane the sum of its 16-lane row. Pure VALU (no DS pipe).
#define DPP_QUAD_XOR1 0xB1         // quad_perm [1,0,3,2]
#define DPP_QUAD_XOR2 0x4E         // quad_perm [2,3,0,1]
#define DPP_ROW_HALF_MIRROR 0x141  // lane ^ 7 within 8
#define DPP_ROW_MIRROR 0x140       // lane ^ 15 within 16

template <int CTRL>
__device__ __forceinline__ float dpp_add(float v) {
    int perm = __builtin_amdgcn_update_dpp(0, __float_as_int(v), CTRL, 0xF, 0xF, true);
    return v + __int_as_float(perm);
}

__device__ __forceinline__ float row16_sum(float v) {
    v = dpp_add<DPP_QUAD_XOR1>(v);
    v = dpp_add<DPP_QUAD_XOR2>(v);
    v = dpp_add<DPP_ROW_HALF_MIRROR>(v);
    v = dpp_add<DPP_ROW_MIRROR>(v);
    return v;
}

// -----------------------------------------------------------------------------
// Fused kernel: per (b,n) block.
//   Stage 0/1: redundantly compute u[h][c] = sum_d W[c, h*D+d] * q[h,d]
//              (W slice is L2-resident; coalesced 16-lane-cooperative dots).
//              Only the first D rows of W matter: the set-feature half of W,
//              the DeepSets MLP, and Wb contribute a per-(b,n,h) constant
//              that cancels in the softmax over s.
//   Phase 1:   e[s][h] = x[b,n,s,:]·u[h,:]  (coalesced, DPP reduction)
//   Phase 2:   softmax over s (wave w = head w)
//   Phase 3:   coalesced float4 stores of (B,N,S,H) output.
// Pass-0 x loads are issued at kernel top so the HBM x-stream overlaps the
// u-compute (which is L2 traffic).
// -----------------------------------------------------------------------------
__global__ void __launch_bounds__(Sset) attn_fused_kernel(
    const float* __restrict__ x,    // (B,N,S,D)
    const float* __restrict__ W,    // (2D, H*D)
    const float* __restrict__ q,    // (H, D)
    float* __restrict__ out)        // (B,N,S,H)
{
    const int bn = blockIdx.x;      // 0..255
    const int tid = threadIdx.x;    // 0..511
    const int wave = tid >> 6;      // 0..7
    const int lane = tid & 63;
    const int g    = lane >> 4;     // row-group within wave: 0..3
    const int sub  = lane & 15;     // position within row: 0..15

    __shared__ float e_s[Hh * EST];   // 16.4 KB
    __shared__ float us[Hh * Din];    // 4 KB
    __shared__ float qs[Hh * Din];    // 4 KB

    // ---- issue pass-0 x loads immediately: start the HBM stream at t=0 ----
    const float4* xb = (const float4*)(x + (size_t)bn * Sset * Din);
    const int r0 = wave * 64 + g;
    float4 px0 = xb[(size_t)r0 * (Din / 4) + sub];
    float4 px1 = xb[(size_t)r0 * (Din / 4) + sub + 16];

    // ---- Stage 0: q -> LDS (coalesced float2) -----------------------------
    {
        const float2* q2 = (const float2*)q;
        ((float2*)qs)[tid] = q2[tid];
    }
    __syncthreads();

    // ---- Stage 1: u[h][c]; 16-lane group per dot, 32 dots/block-pass ------
    // dot index idx = p*32 + wave*4 + g covers 0..1023; h=idx>>7, c=idx&127.
#pragma unroll 4
    for (int p = 0; p < 32; ++p) {
        const int idx = p * 32 + wave * 4 + g;
        const int h = idx >> 7;
        const int c = idx & 127;
        const float4* Wr = (const float4*)(W + (size_t)c * (Hh * Din) + (size_t)h * Din);
        const float4* qr = (const float4*)(qs + h * Din);
        const float4 w0 = Wr[sub];
        const float4 w1 = Wr[sub + 16];
        const float4 q0 = qr[sub];
        const float4 q1 = qr[sub + 16];
        float v;
        v = w0.x * q0.x;
        v = fmaf(w0.y, q0.y, v);
        v = fmaf(w0.z, q0.z, v);
        v = fmaf(w0.w, q0.w, v);
        v = fmaf(w1.x, q1.x, v);
        v = fmaf(w1.y, q1.y, v);
        v = fmaf(w1.z, q1.z, v);
        v = fmaf(w1.w, q1.w, v);
        v = row16_sum(v);
        if (sub == 0) us[idx] = v;
    }
    __syncthreads();

    // ---- preload u fragments from LDS: u[h][4*sub..], u[h][64+4*sub..] ----
    const float4* u4 = (const float4*)us;
    float4 ua[Hh], ub[Hh];
#pragma unroll
    for (int h = 0; h < Hh; ++h) {
        ua[h] = u4[h * 32 + sub];
        ub[h] = u4[h * 32 + sub + 16];
    }

    // ---- Phase 1: e[s][h]; wave handles rows wave*64 .. wave*64+63,
    //      4 rows per pass (one per 16-lane group), 16 passes, 1-deep prefetch.
#pragma unroll 4
    for (int pass = 0; pass < 16; ++pass) {
        const int r = wave * 64 + pass * 4 + g;
        const float4 x0 = px0;
        const float4 x1 = px1;
        if (pass < 15) {
            const float4* xn = xb + (size_t)(r + 4) * (Din / 4);
            px0 = xn[sub];
            px1 = xn[sub + 16];
        }

        float st = 0.f;
#pragma unroll
        for (int h = 0; h < Hh; ++h) {
            float v;
            v = x0.x * ua[h].x;
            v = fmaf(x0.y, ua[h].y, v);
            v = fmaf(x0.z, ua[h].z, v);
            v = fmaf(x0.w, ua[h].w, v);
            v = fmaf(x1.x, ub[h].x, v);
            v = fmaf(x1.y, ub[h].y, v);
            v = fmaf(x1.z, ub[h].z, v);
            v = fmaf(x1.w, ub[h].w, v);
            v = row16_sum(v);       // all 16 lanes get the row sum
            if (sub == h) st = v;   // lane h of each group keeps e[r][h]
        }
        if (sub < Hh) e_s[sub * EST + r] = st;
    }
    __syncthreads();

    // ---- Phase 2: softmax over s; wave w handles head w ------------------
    {
        float* eh = &e_s[wave * EST];

        float m = -1e30f;
#pragma unroll
        for (int k = 0; k < Sset / 64; ++k) m = fmaxf(m, eh[lane + 64 * k]);
#pragma unroll
        for (int off = 32; off >= 1; off >>= 1) m = fmaxf(m, __shfl_xor(m, off, 64));

        float p[Sset / 64];
        float sum = 0.f;
#pragma unroll
        for (int k = 0; k < Sset / 64; ++k) {
            p[k] = __expf(eh[lane + 64 * k] - m);
            sum += p[k];
        }
#pragma unroll
        for (int off = 32; off >= 1; off >>= 1) sum += __shfl_xor(sum, off, 64);

        const float inv = 1.f / sum;
#pragma unroll
        for (int k = 0; k < Sset / 64; ++k) eh[lane + 64 * k] = p[k] * inv;
    }
    __syncthreads();

    // ---- Phase 3: coalesced write out[(bn*S + s)*H + h] ------------------
    {
        const int s = tid;
        float4 o0, o1;
        o0.x = e_s[0 * EST + s];
        o0.y = e_s[1 * EST + s];
        o0.z = e_s[2 * EST + s];
        o0.w = e_s[3 * EST + s];
        o1.x = e_s[4 * EST + s];
        o1.y = e_s[5 * EST + s];
        o1.z = e_s[6 * EST + s];
        o1.w = e_s[7 * EST + s];
        float4* orow = (float4*)(out + ((size_t)bn * Sset + s) * Hh);
        orow[0] = o0;
        orow[1] = o1;
    }
}

extern "C" void kernel_launch(void* const* d_in, const int* in_sizes, int n_in,
                              void* d_out, int out_size, void* d_ws, size_t ws_size,
                              hipStream_t stream) {
    // setup_inputs order: x, w1, b1, w2, b2, w3, b3, W, Wb, q
    const float* x = (const float*)d_in[0];
    const float* W = (const float*)d_in[7];
    const float* q = (const float*)d_in[9];
    float* out = (float*)d_out;

    attn_fused_kernel<<<dim3(Bsz * Ngrp), dim3(Sset), 0, stream>>>(x, W, q, out);
}

// Round 5
// 118.029 us; speedup vs baseline: 1.0338x; 1.0338x over previous
//
#include <hip/hip_runtime.h>

// Problem constants (from reference): B=4, N=64, S=512, D=128, H=8
#define Bsz 4
#define Ngrp 64
#define Sset 512
#define Din 128
#define Hh 8
#define EST (Sset + 1)  // padded LDS stride for e rows

// DPP-based add over lanes: masks {1,2,7,15} generate the full 16-lane group,
// so 4 steps give every lane the sum of its 16-lane row. Pure VALU (no DS pipe).
#define DPP_QUAD_XOR1 0xB1         // quad_perm [1,0,3,2]
#define DPP_QUAD_XOR2 0x4E         // quad_perm [2,3,0,1]
#define DPP_ROW_HALF_MIRROR 0x141  // lane ^ 7 within 8
#define DPP_ROW_MIRROR 0x140       // lane ^ 15 within 16

template <int CTRL>
__device__ __forceinline__ float dpp_add(float v) {
    int perm = __builtin_amdgcn_update_dpp(0, __float_as_int(v), CTRL, 0xF, 0xF, true);
    return v + __int_as_float(perm);
}

__device__ __forceinline__ float row16_sum(float v) {
    v = dpp_add<DPP_QUAD_XOR1>(v);
    v = dpp_add<DPP_QUAD_XOR2>(v);
    v = dpp_add<DPP_ROW_HALF_MIRROR>(v);
    v = dpp_add<DPP_ROW_MIRROR>(v);
    return v;
}

// -----------------------------------------------------------------------------
// Kernel A: u[h][c] = sum_d W[c, h*D+d] * q[h, d].
// Only the first D rows of W matter: the set-feature half of W, the DeepSets
// MLP, and Wb contribute a per-(b,n,h) constant that cancels in the softmax
// over s. One 16-lane group per dot, 16 dots per 256-thread block, single
// pass; W reads are coalesced 256 B runs. h = blockIdx.x>>3 is block-uniform.
// -----------------------------------------------------------------------------
__global__ void __launch_bounds__(256) compute_u_kernel(
    const float* __restrict__ W,   // (2D, H*D) row-major
    const float* __restrict__ q,   // (H, D)
    float* __restrict__ u)         // (H, D) out
{
    const int tid = threadIdx.x;   // 0..255
    const int grp = tid >> 4;      // 0..15  (dot within block)
    const int sub = tid & 15;      // 0..15  (position within dot)

    const int idx = blockIdx.x * 16 + grp;   // 0..1023
    const int h = idx >> 7;                  // block-uniform
    const int c = idx & 127;

    const float4* Wr = (const float4*)(W + (size_t)c * (Hh * Din) + (size_t)h * Din);
    const float4* qr = (const float4*)(q + h * Din);
    const float4 w0 = Wr[sub];
    const float4 w1 = Wr[sub + 16];
    const float4 q0 = qr[sub];
    const float4 q1 = qr[sub + 16];

    float v;
    v = w0.x * q0.x;
    v = fmaf(w0.y, q0.y, v);
    v = fmaf(w0.z, q0.z, v);
    v = fmaf(w0.w, q0.w, v);
    v = fmaf(w1.x, q1.x, v);
    v = fmaf(w1.y, q1.y, v);
    v = fmaf(w1.z, q1.z, v);
    v = fmaf(w1.w, q1.w, v);
    v = row16_sum(v);
    if (sub == 0) u[idx] = v;
}

// -----------------------------------------------------------------------------
// Kernel B: per (b,n) block: e[s][h] = x[b,n,s,:]·u[h,:], softmax over s,
// write out (B,N,S,H).
//
// Phase 1: 16 lanes cooperate per s-row (coalesced 256 B runs); u preloaded
// into 16 float4 regs/thread; 16-lane reduction via DPP (VALU-only).
// -----------------------------------------------------------------------------
__global__ void __launch_bounds__(Sset) attn_softmax_kernel(
    const float* __restrict__ x,    // (B,N,S,D)
    const float* __restrict__ u,    // (H,D)
    float* __restrict__ out)        // (B,N,S,H)
{
    const int bn = blockIdx.x;      // 0..255
    const int tid = threadIdx.x;    // 0..511
    const int wave = tid >> 6;      // 0..7
    const int lane = tid & 63;
    const int g    = lane >> 4;     // row-group within wave: 0..3
    const int sub  = lane & 15;     // position within row: 0..15

    __shared__ float e_s[Hh * EST];

    // ---- preload u fragments: lane needs u[h][4*sub..] and u[h][64+4*sub..]
    const float4* u4 = (const float4*)u;
    float4 ua[Hh], ub[Hh];
#pragma unroll
    for (int h = 0; h < Hh; ++h) {
        ua[h] = u4[h * 32 + sub];
        ub[h] = u4[h * 32 + sub + 16];
    }

    // ---- Phase 1: e[s][h]; wave handles rows wave*64 .. wave*64+63,
    //      4 rows per pass (one per 16-lane group), 16 passes.
    const float4* xb = (const float4*)(x + (size_t)bn * Sset * Din);
#pragma unroll 4
    for (int pass = 0; pass < 16; ++pass) {
        const int r = wave * 64 + pass * 4 + g;
        const float4* xr = xb + (size_t)r * (Din / 4);
        const float4 x0 = xr[sub];
        const float4 x1 = xr[sub + 16];

        float st = 0.f;
#pragma unroll
        for (int h = 0; h < Hh; ++h) {
            float v;
            v = x0.x * ua[h].x;
            v = fmaf(x0.y, ua[h].y, v);
            v = fmaf(x0.z, ua[h].z, v);
            v = fmaf(x0.w, ua[h].w, v);
            v = fmaf(x1.x, ub[h].x, v);
            v = fmaf(x1.y, ub[h].y, v);
            v = fmaf(x1.z, ub[h].z, v);
            v = fmaf(x1.w, ub[h].w, v);
            v = row16_sum(v);       // DPP: all 16 lanes get the row sum
            if (sub == h) st = v;   // lane h of each group keeps e[r][h]
        }
        if (sub < Hh) e_s[sub * EST + r] = st;
    }
    __syncthreads();

    // ---- Phase 2: softmax over s; wave w handles head w ------------------
    {
        float* eh = &e_s[wave * EST];

        float m = -1e30f;
#pragma unroll
        for (int k = 0; k < Sset / 64; ++k) m = fmaxf(m, eh[lane + 64 * k]);
#pragma unroll
        for (int off = 32; off >= 1; off >>= 1) m = fmaxf(m, __shfl_xor(m, off, 64));

        float p[Sset / 64];
        float sum = 0.f;
#pragma unroll
        for (int k = 0; k < Sset / 64; ++k) {
            p[k] = __expf(eh[lane + 64 * k] - m);
            sum += p[k];
        }
#pragma unroll
        for (int off = 32; off >= 1; off >>= 1) sum += __shfl_xor(sum, off, 64);

        const float inv = 1.f / sum;
#pragma unroll
        for (int k = 0; k < Sset / 64; ++k) eh[lane + 64 * k] = p[k] * inv;
    }
    __syncthreads();

    // ---- Phase 3: coalesced write out[(bn*S + s)*H + h] ------------------
    {
        const int s = tid;
        float4 o0, o1;
        o0.x = e_s[0 * EST + s];
        o0.y = e_s[1 * EST + s];
        o0.z = e_s[2 * EST + s];
        o0.w = e_s[3 * EST + s];
        o1.x = e_s[4 * EST + s];
        o1.y = e_s[5 * EST + s];
        o1.z = e_s[6 * EST + s];
        o1.w = e_s[7 * EST + s];
        float4* orow = (float4*)(out + ((size_t)bn * Sset + s) * Hh);
        orow[0] = o0;
        orow[1] = o1;
    }
}

extern "C" void kernel_launch(void* const* d_in, const int* in_sizes, int n_in,
                              void* d_out, int out_size, void* d_ws, size_t ws_size,
                              hipStream_t stream) {
    // setup_inputs order: x, w1, b1, w2, b2, w3, b3, W, Wb, q
    const float* x = (const float*)d_in[0];
    const float* W = (const float*)d_in[7];
    const float* q = (const float*)d_in[9];
    float* u = (float*)d_ws;            // H*D floats = 4 KB scratch
    float* out = (float*)d_out;

    compute_u_kernel<<<dim3(64), dim3(256), 0, stream>>>(W, q, u);
    attn_softmax_kernel<<<dim3(Bsz * Ngrp), dim3(Sset), 0, stream>>>(x, u, out);
}